// Round 1
// baseline (469.877 us; speedup 1.0000x reference)
//
#include <hip/hip_runtime.h>
#include <cstdint>
#include <cstddef>

#define TT    4096          // sequence length
#define NB    4             // batch
#define DIMV  1024
#define MTOT  (NB*TT)       // 16384 rows
#define KK    1024          // GEMM K
#define NCOL  4096          // GEMM N (4*DIM)
#define NCH   64            // scan chunks
#define CL    (TT/NCH)      // 64 steps per chunk

typedef _Float16 half8 __attribute__((ext_vector_type(8)));
typedef float    f32x4 __attribute__((ext_vector_type(4)));
typedef __attribute__((address_space(1))) void GV;
typedef __attribute__((address_space(3))) void LV;

__device__ __forceinline__ void gload16(const void* g, void* l) {
    __builtin_amdgcn_global_load_lds((GV*)g, (LV*)l, 16, 0, 0);
}

__device__ __forceinline__ float softplus_f(float x) {
    return fmaxf(x, 0.0f) + log1pf(expf(-fabsf(x)));
}

// ---------- conversions ----------
__global__ __launch_bounds__(256) void k_cvt_x(const float* __restrict__ x,
                                               _Float16* __restrict__ Xs) {
    int idx = blockIdx.x * 256 + threadIdx.x;   // 16.7M threads, [16384][1024]
    Xs[idx] = (_Float16)x[idx];
}

// W [1024][4096] fp32 -> Wt [4096][1024] fp16 (transposed, N-major for B^T GEMM)
__global__ __launch_bounds__(256) void k_cvt_w(const float* __restrict__ W,
                                               _Float16* __restrict__ Wt) {
    __shared__ float tile[32][33];
    int tx = threadIdx.x & 31, ty = threadIdx.x >> 5;   // 32 x 8
    int nb = blockIdx.x * 32, kb = blockIdx.y * 32;
#pragma unroll
    for (int j = 0; j < 32; j += 8)
        tile[ty + j][tx] = W[(size_t)(kb + ty + j) * NCOL + nb + tx];
    __syncthreads();
#pragma unroll
    for (int j = 0; j < 32; j += 8)
        Wt[(size_t)(nb + ty + j) * KK + kb + tx] = (_Float16)tile[tx][ty + j];
}

// ---------- GEMM + fused gate activations ----------
// A = Xs [16384][1024] f16 row-major, Bt = Wt [4096][1024] f16 row-major.
// 128x128 tile, BK=32, 4 waves (2x2), each wave 64x64 via 4x4 frags of 16x16x32.
__global__ __launch_bounds__(256) void k_gemm_gates(
    const _Float16* __restrict__ Xs, const _Float16* __restrict__ Wt,
    const float* __restrict__ bias, const float* __restrict__ ibias,
    float* __restrict__ gi, float* __restrict__ gf,
    _Float16* __restrict__ go, _Float16* __restrict__ gtz)
{
    __shared__ __align__(16) _Float16 Al[128 * 32];
    __shared__ __align__(16) _Float16 Bl[128 * 32];
    const int tid  = threadIdx.x;
    const int lane = tid & 63;
    const int wave = tid >> 6;
    const int m0 = blockIdx.y * 128;
    const int n0 = blockIdx.x * 128;
    const int wm = (wave >> 1) * 64;
    const int wn = (wave & 1) * 64;

    // staging: thread stages 16B at LDS byte offset tid*16 (wave-uniform base + lane*16)
    const int r0 = tid >> 2;            // 0..63
    const int c0 = (tid & 3) * 8;       // 0,8,16,24
    const _Float16* aSrc = Xs + (size_t)(m0 + r0) * KK + c0;
    const _Float16* bSrc = Wt + (size_t)(n0 + r0) * KK + c0;
    _Float16* aDst = Al + tid * 8;
    _Float16* bDst = Bl + tid * 8;

    f32x4 acc[4][4] = {};
    const int lr  = lane & 15;
    const int lg8 = (lane >> 4) * 8;

    for (int kk = 0; kk < KK; kk += 32) {
        __syncthreads();                              // prev iter's LDS reads done
        gload16(aSrc + kk, aDst);
        gload16(aSrc + (size_t)64 * KK + kk, aDst + 2048);
        gload16(bSrc + kk, bDst);
        gload16(bSrc + (size_t)64 * KK + kk, bDst + 2048);
        __syncthreads();                              // vmcnt drained by compiler

        half8 af[4], bfr[4];
#pragma unroll
        for (int mi = 0; mi < 4; ++mi)
            af[mi] = *(const half8*)&Al[(wm + mi * 16 + lr) * 32 + lg8];
#pragma unroll
        for (int nj = 0; nj < 4; ++nj)
            bfr[nj] = *(const half8*)&Bl[(wn + nj * 16 + lr) * 32 + lg8];
#pragma unroll
        for (int mi = 0; mi < 4; ++mi)
#pragma unroll
            for (int nj = 0; nj < 4; ++nj)
                acc[mi][nj] = __builtin_amdgcn_mfma_f32_16x16x32_f16(
                    af[mi], bfr[nj], acc[mi][nj], 0, 0, 0);
    }

    // epilogue: C/D layout col=lane&15, row=(lane>>4)*4+reg  [m89-verified]
    const int gate = n0 >> 10;          // block-uniform: 128 | 1024
#pragma unroll
    for (int mi = 0; mi < 4; ++mi) {
        const int rowb = m0 + wm + mi * 16 + (lane >> 4) * 4;
#pragma unroll
        for (int nj = 0; nj < 4; ++nj) {
            const int col = n0 + wn + nj * 16 + lr;
            const int d   = col & 1023;
            const float bb = bias[col];
#pragma unroll
            for (int r = 0; r < 4; ++r) {
                float v = acc[mi][nj][r] + bb;
                const int idx = (rowb + r) * DIMV + d;
                if (gate == 0) {
                    gi[idx] = 10.0f * tanhf((v + ibias[d]) * 0.1f);   // softcap(i+ib)
                } else if (gate == 1) {
                    gf[idx] = -softplus_f(v);                          // log-forget
                } else if (gate == 2) {
                    go[idx] = (_Float16)(1.0f / (1.0f + expf(-v)));    // sigmoid
                } else {
                    gtz[idx] = (_Float16)tanhf(v);                     // tanh(z)
                }
            }
        }
    }
}

// ---------- chunked scan ----------
// pass1: per (channel, chunk) local scan from identity (m=-1e30): {F=sum f, M, c, n}
__global__ __launch_bounds__(256) void k_scan1(
    const float* __restrict__ gi, const float* __restrict__ gf,
    const _Float16* __restrict__ gtz, float4* __restrict__ sums)
{
    const int ch = blockIdx.x * 256 + threadIdx.x;   // 0..4095
    const int chunk = blockIdx.y;
    const int b = ch >> 10, d = ch & 1023;
    int base = (b * TT + chunk * CL) * DIMV + d;
    float m = -1e30f, c = 0.0f, n = 0.0f, F = 0.0f;
#pragma unroll 4
    for (int t = 0; t < CL; ++t, base += DIMV) {
        const float iv = gi[base];
        const float fv = gf[base];
        const float zv = (float)gtz[base];
        F += fv;
        const float mn = fmaxf(fv + m, iv);
        const float sc = __expf(fv + m - mn);
        const float si = __expf(iv - mn);
        c = sc * c + si * zv;
        n = sc * n + si;
        m = mn;
    }
    sums[chunk * 4096 + ch] = make_float4(F, m, c, n);
}

// pass2: sequential combine over chunks; emit incoming state per chunk
__global__ __launch_bounds__(256) void k_scan2(const float4* __restrict__ sums,
                                               float4* __restrict__ states) {
    const int ch = blockIdx.x * 256 + threadIdx.x;
    float m = -1e30f, c = 0.0f, n = 0.0f;
    for (int chunk = 0; chunk < NCH; ++chunk) {
        states[chunk * 4096 + ch] = make_float4(m, c, n, 0.0f);
        const float4 s = sums[chunk * 4096 + ch];
        const float mn = fmaxf(m + s.x, s.y);
        const float e1 = __expf(m + s.x - mn);
        const float e2 = __expf(s.y - mn);
        c = e1 * c + e2 * s.z;
        n = e1 * n + e2 * s.w;
        m = mn;
    }
}

// pass3: re-scan chunk from incoming state, emit h into d_out
__global__ __launch_bounds__(256) void k_scan3(
    const float* __restrict__ gi, const float* __restrict__ gf,
    const _Float16* __restrict__ go, const _Float16* __restrict__ gtz,
    const float4* __restrict__ states, float* __restrict__ out)
{
    const int ch = blockIdx.x * 256 + threadIdx.x;
    const int chunk = blockIdx.y;
    const int b = ch >> 10, d = ch & 1023;
    int base = (b * TT + chunk * CL) * DIMV + d;
    const float4 st = states[chunk * 4096 + ch];
    float m = st.x, c = st.y, n = st.z;
#pragma unroll 4
    for (int t = 0; t < CL; ++t, base += DIMV) {
        const float iv = gi[base];
        const float fv = gf[base];
        const float ov = (float)go[base];
        const float zv = (float)gtz[base];
        const float mn = fmaxf(fv + m, iv);
        const float sc = __expf(fv + m - mn);
        const float si = __expf(iv - mn);
        c = sc * c + si * zv;
        n = sc * n + si;
        m = mn;
        out[base] = ov * c / (n + 1e-6f);
    }
}

// ---------- RMSNorm in place on d_out: one wave per 1024-row ----------
__global__ __launch_bounds__(256) void k_rmsnorm(float* __restrict__ out,
                                                 const float* __restrict__ scale) {
    const int wid = threadIdx.x >> 6, lane = threadIdx.x & 63;
    const int row = blockIdx.x * 4 + wid;
    float4* p = (float4*)(out + (size_t)row * DIMV);
    const float4* sc = (const float4*)scale;
    float4 v[4];
    float ss = 0.0f;
#pragma unroll
    for (int j = 0; j < 4; ++j) {
        v[j] = p[j * 64 + lane];
        ss += v[j].x * v[j].x + v[j].y * v[j].y + v[j].z * v[j].z + v[j].w * v[j].w;
    }
#pragma unroll
    for (int off = 32; off > 0; off >>= 1) ss += __shfl_xor(ss, off, 64);
    const float inv = 1.0f / sqrtf(ss * (1.0f / 1024.0f) + 1e-8f);
#pragma unroll
    for (int j = 0; j < 4; ++j) {
        const float4 s = sc[j * 64 + lane];
        float4 o;
        o.x = v[j].x * inv * s.x;
        o.y = v[j].y * inv * s.y;
        o.z = v[j].z * inv * s.z;
        o.w = v[j].w * inv * s.w;
        p[j * 64 + lane] = o;
    }
}

extern "C" void kernel_launch(void* const* d_in, const int* in_sizes, int n_in,
                              void* d_out, int out_size, void* d_ws, size_t ws_size,
                              hipStream_t stream) {
    (void)in_sizes; (void)n_in; (void)out_size; (void)ws_size;
    const float* x     = (const float*)d_in[0];
    const float* W     = (const float*)d_in[1];
    const float* bias  = (const float*)d_in[2];
    const float* ibias = (const float*)d_in[3];
    const float* scale = (const float*)d_in[4];
    float* out = (float*)d_out;

    char* ws = (char*)d_ws;
    size_t off = 0;
    _Float16* Xs = (_Float16*)(ws + off); off += (size_t)MTOT * KK * 2;     //  33.5 MB
    _Float16* Wt = (_Float16*)(ws + off); off += (size_t)NCOL * KK * 2;     //   8.4 MB
    float*    gi = (float*)(ws + off);    off += (size_t)MTOT * DIMV * 4;   //  67.1 MB
    float*    gf = (float*)(ws + off);    off += (size_t)MTOT * DIMV * 4;   //  67.1 MB
    _Float16* go = (_Float16*)(ws + off); off += (size_t)MTOT * DIMV * 2;   //  33.5 MB
    _Float16* gtz= (_Float16*)(ws + off); off += (size_t)MTOT * DIMV * 2;   //  33.5 MB
    float4* sums   = (float4*)(ws + off); off += (size_t)NCH * 4096 * 16;   //   4.2 MB
    float4* states = (float4*)(ws + off); off += (size_t)NCH * 4096 * 16;   //   4.2 MB

    k_cvt_x<<<(MTOT * DIMV) / 256, 256, 0, stream>>>(x, Xs);
    k_cvt_w<<<dim3(NCOL / 32, KK / 32), 256, 0, stream>>>(W, Wt);
    k_gemm_gates<<<dim3(NCOL / 128, MTOT / 128), 256, 0, stream>>>(
        Xs, Wt, bias, ibias, gi, gf, go, gtz);
    k_scan1<<<dim3(16, NCH), 256, 0, stream>>>(gi, gf, gtz, sums);
    k_scan2<<<16, 256, 0, stream>>>(sums, states);
    k_scan3<<<dim3(16, NCH), 256, 0, stream>>>(gi, gf, go, gtz, states, out);
    k_rmsnorm<<<MTOT / 4, 256, 0, stream>>>(out, scale);
}

// Round 2
// 378.037 us; speedup vs baseline: 1.2429x; 1.2429x over previous
//
#include <hip/hip_runtime.h>
#include <cstdint>
#include <cstddef>

#define TT    4096          // sequence length
#define NB    4             // batch
#define DIMV  1024
#define MTOT  (NB*TT)       // 16384 rows
#define KK    1024          // GEMM K
#define NCOL  4096          // GEMM N (4*DIM)
#define NCH   64            // scan chunks
#define CL    (TT/NCH)      // 64 steps per chunk

typedef _Float16 half8 __attribute__((ext_vector_type(8)));
typedef float    f32x4 __attribute__((ext_vector_type(4)));
typedef __attribute__((address_space(1))) void GV;
typedef __attribute__((address_space(3))) void LV;

__device__ __forceinline__ void gload16(const void* g, void* l) {
    __builtin_amdgcn_global_load_lds((GV*)g, (LV*)l, 16, 0, 0);
}

// fast activations: v_exp_f32 / v_log_f32 based, overflow-safe
__device__ __forceinline__ float ftanh(float x) {          // 1 - 2/(e^2x+1)
    return 1.0f - 2.0f / (__expf(2.0f * x) + 1.0f);
}
__device__ __forceinline__ float fsig(float x) {
    return 1.0f / (1.0f + __expf(-x));
}
__device__ __forceinline__ float fsoftplus(float x) {
    return fmaxf(x, 0.0f) + __logf(1.0f + __expf(-fabsf(x)));
}

// ---------- conversions ----------
__global__ __launch_bounds__(256) void k_cvt_x(const float* __restrict__ x,
                                               _Float16* __restrict__ Xs) {
    int idx = blockIdx.x * 256 + threadIdx.x;   // 16.7M threads, [16384][1024]
    Xs[idx] = (_Float16)x[idx];
}

// W [1024][4096] fp32 -> Wt [4096][1024] fp16 (transposed, N-major for B^T GEMM)
__global__ __launch_bounds__(256) void k_cvt_w(const float* __restrict__ W,
                                               _Float16* __restrict__ Wt) {
    __shared__ float tile[32][33];
    int tx = threadIdx.x & 31, ty = threadIdx.x >> 5;   // 32 x 8
    int nb = blockIdx.x * 32, kb = blockIdx.y * 32;
#pragma unroll
    for (int j = 0; j < 32; j += 8)
        tile[ty + j][tx] = W[(size_t)(kb + ty + j) * NCOL + nb + tx];
    __syncthreads();
#pragma unroll
    for (int j = 0; j < 32; j += 8)
        Wt[(size_t)(nb + ty + j) * KK + kb + tx] = (_Float16)tile[tx][ty + j];
}

// ---------- GEMM + fused gate activations ----------
// A = Xs [16384][1024] f16 row-major, Bt = Wt [4096][1024] f16 row-major.
// 128x128 tile, BK=32, 4 waves (2x2), each wave 64x64 via 4x4 frags of 16x16x32.
// LDS tile [row][32] f16: 64B rows. Anti-conflict swizzle: physical 16B slot s
// holds logical slot s ^ ((row>>1)&3)  (rule 21: linear LDS dest, pre-swizzled
// global source, same XOR on the read side).
__global__ __launch_bounds__(256) void k_gemm_gates(
    const _Float16* __restrict__ Xs, const _Float16* __restrict__ Wt,
    const float* __restrict__ bias, const float* __restrict__ ibias,
    float* __restrict__ gi, float* __restrict__ gf,
    _Float16* __restrict__ go, _Float16* __restrict__ gtz)
{
    __shared__ __align__(16) _Float16 Al[128 * 32];
    __shared__ __align__(16) _Float16 Bl[128 * 32];
    const int tid  = threadIdx.x;
    const int lane = tid & 63;
    const int wave = tid >> 6;
    const int m0 = blockIdx.y * 128;
    const int n0 = blockIdx.x * 128;
    const int wm = (wave >> 1) * 64;
    const int wn = (wave & 1) * 64;

    // staging: thread stages 16B at LDS byte offset tid*16 = (row r0, slot tid&3).
    // Source column is the SWIZZLED logical slot for that physical position.
    const int r0   = tid >> 2;                       // 0..63
    const int slot = tid & 3;
    const int swz  = slot ^ ((r0 >> 1) & 3);         // same for row r0+64 (64 even)
    const _Float16* aSrc = Xs + (size_t)(m0 + r0) * KK + swz * 8;
    const _Float16* bSrc = Wt + (size_t)(n0 + r0) * KK + swz * 8;
    _Float16* aDst = Al + tid * 8;
    _Float16* bDst = Bl + tid * 8;

    f32x4 acc[4][4] = {};
    const int lr = lane & 15;
    // read-side physical slot: logical slot (lane>>4) XOR row-swizzle; row =
    // wm+mi*16+lr, and (wm+mi*16)>>1 is a multiple of 8 -> only lr matters.
    const int ps = ((lane >> 4) ^ ((lr >> 1) & 3)) * 8;   // element offset in row

    for (int kk = 0; kk < KK; kk += 32) {
        __syncthreads();                              // prev iter's LDS reads done
        gload16(aSrc + kk, aDst);
        gload16(aSrc + (size_t)64 * KK + kk, aDst + 2048);
        gload16(bSrc + kk, bDst);
        gload16(bSrc + (size_t)64 * KK + kk, bDst + 2048);
        __syncthreads();                              // vmcnt drained by compiler

        half8 af[4], bfr[4];
#pragma unroll
        for (int mi = 0; mi < 4; ++mi)
            af[mi] = *(const half8*)&Al[(wm + mi * 16 + lr) * 32 + ps];
#pragma unroll
        for (int nj = 0; nj < 4; ++nj)
            bfr[nj] = *(const half8*)&Bl[(wn + nj * 16 + lr) * 32 + ps];
#pragma unroll
        for (int mi = 0; mi < 4; ++mi)
#pragma unroll
            for (int nj = 0; nj < 4; ++nj)
                acc[mi][nj] = __builtin_amdgcn_mfma_f32_16x16x32_f16(
                    af[mi], bfr[nj], acc[mi][nj], 0, 0, 0);
    }

    // epilogue: C/D layout col=lane&15, row=(lane>>4)*4+reg  [m89-verified]
    const int gate = n0 >> 10;          // block-uniform: one gate per block
#pragma unroll
    for (int mi = 0; mi < 4; ++mi) {
        const int rowb = m0 + wm + mi * 16 + (lane >> 4) * 4;
#pragma unroll
        for (int nj = 0; nj < 4; ++nj) {
            const int col = n0 + wn + nj * 16 + lr;
            const int d   = col & 1023;
            const float bb = bias[col];
#pragma unroll
            for (int r = 0; r < 4; ++r) {
                float v = acc[mi][nj][r] + bb;
                const int idx = (rowb + r) * DIMV + d;
                if (gate == 0) {
                    gi[idx] = 10.0f * ftanh((v + ibias[d]) * 0.1f);   // softcap(i+ib)
                } else if (gate == 1) {
                    gf[idx] = -fsoftplus(v);                           // log-forget
                } else if (gate == 2) {
                    go[idx] = (_Float16)fsig(v);                       // sigmoid
                } else {
                    gtz[idx] = (_Float16)ftanh(v);                     // tanh(z)
                }
            }
        }
    }
}

// ---------- chunked scan ----------
// pass1: per (channel, chunk) local scan from identity (m=-1e30): {F=sum f, M, c, n}
__global__ __launch_bounds__(256) void k_scan1(
    const float* __restrict__ gi, const float* __restrict__ gf,
    const _Float16* __restrict__ gtz, float4* __restrict__ sums)
{
    const int ch = blockIdx.x * 256 + threadIdx.x;   // 0..4095
    const int chunk = blockIdx.y;
    const int b = ch >> 10, d = ch & 1023;
    int base = (b * TT + chunk * CL) * DIMV + d;
    float m = -1e30f, c = 0.0f, n = 0.0f, F = 0.0f;
#pragma unroll 4
    for (int t = 0; t < CL; ++t, base += DIMV) {
        const float iv = gi[base];
        const float fv = gf[base];
        const float zv = (float)gtz[base];
        F += fv;
        const float mn = fmaxf(fv + m, iv);
        const float sc = __expf(fv + m - mn);
        const float si = __expf(iv - mn);
        c = sc * c + si * zv;
        n = sc * n + si;
        m = mn;
    }
    sums[chunk * 4096 + ch] = make_float4(F, m, c, n);
}

// pass2: sequential combine over chunks; emit incoming state per chunk
__global__ __launch_bounds__(256) void k_scan2(const float4* __restrict__ sums,
                                               float4* __restrict__ states) {
    const int ch = blockIdx.x * 256 + threadIdx.x;
    float m = -1e30f, c = 0.0f, n = 0.0f;
    for (int chunk = 0; chunk < NCH; ++chunk) {
        states[chunk * 4096 + ch] = make_float4(m, c, n, 0.0f);
        const float4 s = sums[chunk * 4096 + ch];
        const float mn = fmaxf(m + s.x, s.y);
        const float e1 = __expf(m + s.x - mn);
        const float e2 = __expf(s.y - mn);
        c = e1 * c + e2 * s.z;
        n = e1 * n + e2 * s.w;
        m = mn;
    }
}

// pass3: re-scan chunk from incoming state, emit h into d_out
__global__ __launch_bounds__(256) void k_scan3(
    const float* __restrict__ gi, const float* __restrict__ gf,
    const _Float16* __restrict__ go, const _Float16* __restrict__ gtz,
    const float4* __restrict__ states, float* __restrict__ out)
{
    const int ch = blockIdx.x * 256 + threadIdx.x;
    const int chunk = blockIdx.y;
    const int b = ch >> 10, d = ch & 1023;
    int base = (b * TT + chunk * CL) * DIMV + d;
    const float4 st = states[chunk * 4096 + ch];
    float m = st.x, c = st.y, n = st.z;
#pragma unroll 4
    for (int t = 0; t < CL; ++t, base += DIMV) {
        const float iv = gi[base];
        const float fv = gf[base];
        const float ov = (float)go[base];
        const float zv = (float)gtz[base];
        const float mn = fmaxf(fv + m, iv);
        const float sc = __expf(fv + m - mn);
        const float si = __expf(iv - mn);
        c = sc * c + si * zv;
        n = sc * n + si;
        m = mn;
        out[base] = ov * c / (n + 1e-6f);
    }
}

// ---------- RMSNorm in place on d_out: one wave per 1024-row ----------
__global__ __launch_bounds__(256) void k_rmsnorm(float* __restrict__ out,
                                                 const float* __restrict__ scale) {
    const int wid = threadIdx.x >> 6, lane = threadIdx.x & 63;
    const int row = blockIdx.x * 4 + wid;
    float4* p = (float4*)(out + (size_t)row * DIMV);
    const float4* sc = (const float4*)scale;
    float4 v[4];
    float ss = 0.0f;
#pragma unroll
    for (int j = 0; j < 4; ++j) {
        v[j] = p[j * 64 + lane];
        ss += v[j].x * v[j].x + v[j].y * v[j].y + v[j].z * v[j].z + v[j].w * v[j].w;
    }
#pragma unroll
    for (int off = 32; off > 0; off >>= 1) ss += __shfl_xor(ss, off, 64);
    const float inv = 1.0f / sqrtf(ss * (1.0f / 1024.0f) + 1e-8f);
#pragma unroll
    for (int j = 0; j < 4; ++j) {
        const float4 s = sc[j * 64 + lane];
        float4 o;
        o.x = v[j].x * inv * s.x;
        o.y = v[j].y * inv * s.y;
        o.z = v[j].z * inv * s.z;
        o.w = v[j].w * inv * s.w;
        p[j * 64 + lane] = o;
    }
}

extern "C" void kernel_launch(void* const* d_in, const int* in_sizes, int n_in,
                              void* d_out, int out_size, void* d_ws, size_t ws_size,
                              hipStream_t stream) {
    (void)in_sizes; (void)n_in; (void)out_size; (void)ws_size;
    const float* x     = (const float*)d_in[0];
    const float* W     = (const float*)d_in[1];
    const float* bias  = (const float*)d_in[2];
    const float* ibias = (const float*)d_in[3];
    const float* scale = (const float*)d_in[4];
    float* out = (float*)d_out;

    char* ws = (char*)d_ws;
    size_t off = 0;
    _Float16* Xs = (_Float16*)(ws + off); off += (size_t)MTOT * KK * 2;     //  33.5 MB
    _Float16* Wt = (_Float16*)(ws + off); off += (size_t)NCOL * KK * 2;     //   8.4 MB
    float*    gi = (float*)(ws + off);    off += (size_t)MTOT * DIMV * 4;   //  67.1 MB
    float*    gf = (float*)(ws + off);    off += (size_t)MTOT * DIMV * 4;   //  67.1 MB
    _Float16* go = (_Float16*)(ws + off); off += (size_t)MTOT * DIMV * 2;   //  33.5 MB
    _Float16* gtz= (_Float16*)(ws + off); off += (size_t)MTOT * DIMV * 2;   //  33.5 MB
    float4* sums   = (float4*)(ws + off); off += (size_t)NCH * 4096 * 16;   //   4.2 MB
    float4* states = (float4*)(ws + off); off += (size_t)NCH * 4096 * 16;   //   4.2 MB

    k_cvt_x<<<(MTOT * DIMV) / 256, 256, 0, stream>>>(x, Xs);
    k_cvt_w<<<dim3(NCOL / 32, KK / 32), 256, 0, stream>>>(W, Wt);
    k_gemm_gates<<<dim3(NCOL / 128, MTOT / 128), 256, 0, stream>>>(
        Xs, Wt, bias, ibias, gi, gf, go, gtz);
    k_scan1<<<dim3(16, NCH), 256, 0, stream>>>(gi, gf, gtz, sums);
    k_scan2<<<16, 256, 0, stream>>>(sums, states);
    k_scan3<<<dim3(16, NCH), 256, 0, stream>>>(gi, gf, go, gtz, states, out);
    k_rmsnorm<<<MTOT / 4, 256, 0, stream>>>(out, scale);
}

// Round 3
// 374.254 us; speedup vs baseline: 1.2555x; 1.0101x over previous
//
#include <hip/hip_runtime.h>
#include <cstdint>
#include <cstddef>

#define TT    4096          // sequence length
#define NB    4             // batch
#define DIMV  1024
#define MTOT  (NB*TT)       // 16384 rows
#define KK    1024          // GEMM K
#define NCOL  4096          // GEMM N (4*DIM)
#define NCH   64            // scan chunks
#define CL    (TT/NCH)      // 64 steps per chunk

typedef _Float16 half8 __attribute__((ext_vector_type(8)));
typedef float    f32x4 __attribute__((ext_vector_type(4)));
typedef __attribute__((address_space(1))) void GV;
typedef __attribute__((address_space(3))) void LV;

__device__ __forceinline__ void gload16(const void* g, void* l) {
    __builtin_amdgcn_global_load_lds((GV*)g, (LV*)l, 16, 0, 0);
}

// fast activations: v_exp_f32 / v_log_f32 based, overflow-safe
__device__ __forceinline__ float ftanh(float x) {          // 1 - 2/(e^2x+1)
    return 1.0f - 2.0f / (__expf(2.0f * x) + 1.0f);
}
__device__ __forceinline__ float fsig(float x) {
    return 1.0f / (1.0f + __expf(-x));
}
__device__ __forceinline__ float fsoftplus(float x) {
    return fmaxf(x, 0.0f) + __logf(1.0f + __expf(-fabsf(x)));
}

// ---------- conversions ----------
__global__ __launch_bounds__(256) void k_cvt_x(const float* __restrict__ x,
                                               _Float16* __restrict__ Xs) {
    int idx = blockIdx.x * 256 + threadIdx.x;   // [16384][1024]
    Xs[idx] = (_Float16)x[idx];
}

// W [1024][4096] fp32 -> Wt [4096][1024] fp16 (transposed, N-major for B^T GEMM)
__global__ __launch_bounds__(256) void k_cvt_w(const float* __restrict__ W,
                                               _Float16* __restrict__ Wt) {
    __shared__ float tile[32][33];
    int tx = threadIdx.x & 31, ty = threadIdx.x >> 5;   // 32 x 8
    int nb = blockIdx.x * 32, kb = blockIdx.y * 32;
#pragma unroll
    for (int j = 0; j < 32; j += 8)
        tile[ty + j][tx] = W[(size_t)(kb + ty + j) * NCOL + nb + tx];
    __syncthreads();
#pragma unroll
    for (int j = 0; j < 32; j += 8)
        Wt[(size_t)(nb + ty + j) * KK + kb + tx] = (_Float16)tile[tx][ty + j];
}

// ---------- GEMM + fused gate activations ----------
// A = Xs [16384][1024] f16, Bt = Wt [4096][1024] f16 (both row-major).
// 128x128 tile, BK=64 (16 iters, 32 MFMA per barrier-pair), 4 waves (2x2),
// each wave 64x64 via 4x4 frags of 16x16x32, two k-slices per iter.
// LDS tile [128 rows][64 f16] = 128B rows, 8x 16B slots/row.
// Anti-conflict swizzle (rule 21): physical slot s of row r holds logical
// slot s ^ (r&7); linear LDS dest, pre-swizzled global source, XOR on read.
__global__ __launch_bounds__(256) void k_gemm_gates(
    const _Float16* __restrict__ Xs, const _Float16* __restrict__ Wt,
    const float* __restrict__ bias, const float* __restrict__ ibias,
    _Float16* __restrict__ gi, float* __restrict__ gf,
    _Float16* __restrict__ go, _Float16* __restrict__ gtz)
{
    __shared__ __align__(16) _Float16 Al[128 * 64];   // 16 KB
    __shared__ __align__(16) _Float16 Bl[128 * 64];   // 16 KB
    const int tid  = threadIdx.x;
    const int lane = tid & 63;
    const int wave = tid >> 6;
    const int m0 = blockIdx.y * 128;
    const int n0 = blockIdx.x * 128;
    const int wm = (wave >> 1) * 64;
    const int wn = (wave & 1) * 64;

    // staging: thread stages 16B chunks; chunk index (j*256+tid) -> row 32j+(tid>>3),
    // physical slot tid&7. Source col = swizzled logical slot.
    const int rr = tid >> 3;                         // 0..31
    const int sw = (tid & 7) ^ (rr & 7);             // logical slot for this phys slot
    const _Float16* aSrc = Xs + (size_t)(m0 + rr) * KK + sw * 8;
    const _Float16* bSrc = Wt + (size_t)(n0 + rr) * KK + sw * 8;
    _Float16* aDst = Al + tid * 8;
    _Float16* bDst = Bl + tid * 8;

    f32x4 acc[4][4] = {};
    const int lr = lane & 15;
    const int g  = lane >> 4;           // logical slot low bits within k-slice
    const int x7 = lr & 7;              // row&7 for all fragment rows

    for (int kk = 0; kk < KK; kk += 64) {
        __syncthreads();                              // prev iter's LDS reads done
#pragma unroll
        for (int j = 0; j < 4; ++j) {
            gload16(aSrc + (size_t)(32 * j) * KK + kk, aDst + j * 2048);
            gload16(bSrc + (size_t)(32 * j) * KK + kk, bDst + j * 2048);
        }
        __syncthreads();                              // vmcnt drained by compiler

#pragma unroll
        for (int ks = 0; ks < 2; ++ks) {
            const int ps = (((ks * 4 + g) ^ x7)) * 8; // physical slot -> f16 offset
            half8 af[4], bfr[4];
#pragma unroll
            for (int mi = 0; mi < 4; ++mi)
                af[mi] = *(const half8*)&Al[(wm + mi * 16 + lr) * 64 + ps];
#pragma unroll
            for (int nj = 0; nj < 4; ++nj)
                bfr[nj] = *(const half8*)&Bl[(wn + nj * 16 + lr) * 64 + ps];
#pragma unroll
            for (int mi = 0; mi < 4; ++mi)
#pragma unroll
                for (int nj = 0; nj < 4; ++nj)
                    acc[mi][nj] = __builtin_amdgcn_mfma_f32_16x16x32_f16(
                        af[mi], bfr[nj], acc[mi][nj], 0, 0, 0);
        }
    }

    // epilogue: C/D layout col=lane&15, row=(lane>>4)*4+reg  [m89-verified]
    const int gate = n0 >> 10;          // block-uniform: one gate per block
#pragma unroll
    for (int mi = 0; mi < 4; ++mi) {
        const int rowb = m0 + wm + mi * 16 + (lane >> 4) * 4;
#pragma unroll
        for (int nj = 0; nj < 4; ++nj) {
            const int col = n0 + wn + nj * 16 + lr;
            const int d   = col & 1023;
            const float bb = bias[col];
#pragma unroll
            for (int r = 0; r < 4; ++r) {
                float v = acc[mi][nj][r] + bb;
                const int idx = (rowb + r) * DIMV + d;
                if (gate == 0) {
                    gi[idx] = (_Float16)(10.0f * ftanh((v + ibias[d]) * 0.1f));
                } else if (gate == 1) {
                    gf[idx] = -fsoftplus(v);                           // log-forget
                } else if (gate == 2) {
                    go[idx] = (_Float16)fsig(v);                       // sigmoid
                } else {
                    gtz[idx] = (_Float16)ftanh(v);                     // tanh(z)
                }
            }
        }
    }
}

// ---------- chunked scan ----------
// pass1: per (channel, chunk) local scan from identity (m=-1e30): {F=sum f, M, c, n}
__global__ __launch_bounds__(256) void k_scan1(
    const _Float16* __restrict__ gi, const float* __restrict__ gf,
    const _Float16* __restrict__ gtz, float4* __restrict__ sums)
{
    const int ch = blockIdx.x * 256 + threadIdx.x;   // 0..4095
    const int chunk = blockIdx.y;
    const int b = ch >> 10, d = ch & 1023;
    int base = (b * TT + chunk * CL) * DIMV + d;
    float m = -1e30f, c = 0.0f, n = 0.0f, F = 0.0f;
#pragma unroll 4
    for (int t = 0; t < CL; ++t, base += DIMV) {
        const float iv = (float)gi[base];
        const float fv = gf[base];
        const float zv = (float)gtz[base];
        F += fv;
        const float mn = fmaxf(fv + m, iv);
        const float sc = __expf(fv + m - mn);
        const float si = __expf(iv - mn);
        c = sc * c + si * zv;
        n = sc * n + si;
        m = mn;
    }
    sums[chunk * 4096 + ch] = make_float4(F, m, c, n);
}

// pass2: sequential combine over chunks; emit incoming state per chunk
__global__ __launch_bounds__(256) void k_scan2(const float4* __restrict__ sums,
                                               float4* __restrict__ states) {
    const int ch = blockIdx.x * 256 + threadIdx.x;
    float m = -1e30f, c = 0.0f, n = 0.0f;
    for (int chunk = 0; chunk < NCH; ++chunk) {
        states[chunk * 4096 + ch] = make_float4(m, c, n, 0.0f);
        const float4 s = sums[chunk * 4096 + ch];
        const float mn = fmaxf(m + s.x, s.y);
        const float e1 = __expf(m + s.x - mn);
        const float e2 = __expf(s.y - mn);
        c = e1 * c + e2 * s.z;
        n = e1 * n + e2 * s.w;
        m = mn;
    }
}

// pass3: re-scan chunk from incoming state, emit h (fp16) into hbuf
__global__ __launch_bounds__(256) void k_scan3(
    const _Float16* __restrict__ gi, const float* __restrict__ gf,
    const _Float16* __restrict__ go, const _Float16* __restrict__ gtz,
    const float4* __restrict__ states, _Float16* __restrict__ hbuf)
{
    const int ch = blockIdx.x * 256 + threadIdx.x;
    const int chunk = blockIdx.y;
    const int b = ch >> 10, d = ch & 1023;
    int base = (b * TT + chunk * CL) * DIMV + d;
    const float4 st = states[chunk * 4096 + ch];
    float m = st.x, c = st.y, n = st.z;
#pragma unroll 4
    for (int t = 0; t < CL; ++t, base += DIMV) {
        const float iv = (float)gi[base];
        const float fv = gf[base];
        const float ov = (float)go[base];
        const float zv = (float)gtz[base];
        const float mn = fmaxf(fv + m, iv);
        const float sc = __expf(fv + m - mn);
        const float si = __expf(iv - mn);
        c = sc * c + si * zv;
        n = sc * n + si;
        m = mn;
        hbuf[base] = (_Float16)(ov * c / (n + 1e-6f));
    }
}

// ---------- RMSNorm: read h fp16, write fp32 out; one wave per 1024-row ----------
__global__ __launch_bounds__(256) void k_rmsnorm(const _Float16* __restrict__ h,
                                                 const float* __restrict__ scale,
                                                 float* __restrict__ out) {
    const int wid = threadIdx.x >> 6, lane = threadIdx.x & 63;
    const int row = blockIdx.x * 4 + wid;
    const half8* p = (const half8*)(h + (size_t)row * DIMV);  // 128 half8/row
    const float4* sc = (const float4*)scale;
    half8 v0 = p[lane * 2], v1 = p[lane * 2 + 1];             // 16 f16 per lane
    float f[16];
    float ss = 0.0f;
#pragma unroll
    for (int j = 0; j < 8; ++j) { f[j] = (float)v0[j]; f[8 + j] = (float)v1[j]; }
#pragma unroll
    for (int j = 0; j < 16; ++j) ss += f[j] * f[j];
#pragma unroll
    for (int off = 32; off > 0; off >>= 1) ss += __shfl_xor(ss, off, 64);
    const float inv = 1.0f / sqrtf(ss * (1.0f / 1024.0f) + 1e-8f);
    float4* po = (float4*)(out + (size_t)row * DIMV + lane * 16);
#pragma unroll
    for (int q = 0; q < 4; ++q) {
        const float4 s = sc[lane * 4 + q];
        float4 o;
        o.x = f[q * 4 + 0] * inv * s.x;
        o.y = f[q * 4 + 1] * inv * s.y;
        o.z = f[q * 4 + 2] * inv * s.z;
        o.w = f[q * 4 + 3] * inv * s.w;
        po[q] = o;
    }
}

extern "C" void kernel_launch(void* const* d_in, const int* in_sizes, int n_in,
                              void* d_out, int out_size, void* d_ws, size_t ws_size,
                              hipStream_t stream) {
    (void)in_sizes; (void)n_in; (void)out_size; (void)ws_size;
    const float* x     = (const float*)d_in[0];
    const float* W     = (const float*)d_in[1];
    const float* bias  = (const float*)d_in[2];
    const float* ibias = (const float*)d_in[3];
    const float* scale = (const float*)d_in[4];
    float* out = (float*)d_out;

    char* ws = (char*)d_ws;
    size_t off = 0;
    _Float16* Xs = (_Float16*)(ws + off); off += (size_t)MTOT * KK * 2;     //  33.5 MB
    _Float16* Wt = (_Float16*)(ws + off); off += (size_t)NCOL * KK * 2;     //   8.4 MB
    _Float16* gi = (_Float16*)(ws + off); off += (size_t)MTOT * DIMV * 2;   //  33.5 MB
    float*    gf = (float*)(ws + off);    off += (size_t)MTOT * DIMV * 4;   //  67.1 MB
    _Float16* go = (_Float16*)(ws + off); off += (size_t)MTOT * DIMV * 2;   //  33.5 MB
    _Float16* gtz= (_Float16*)(ws + off); off += (size_t)MTOT * DIMV * 2;   //  33.5 MB
    float4* sums   = (float4*)(ws + off); off += (size_t)NCH * 4096 * 16;   //   4.2 MB
    float4* states = (float4*)(ws + off); off += (size_t)NCH * 4096 * 16;   //   4.2 MB
    _Float16* hbuf = Xs;   // Xs is dead after the GEMM; reuse for h (33.5 MB)

    k_cvt_x<<<(MTOT * DIMV) / 256, 256, 0, stream>>>(x, Xs);
    k_cvt_w<<<dim3(NCOL / 32, KK / 32), 256, 0, stream>>>(W, Wt);
    k_gemm_gates<<<dim3(NCOL / 128, MTOT / 128), 256, 0, stream>>>(
        Xs, Wt, bias, ibias, gi, gf, go, gtz);
    k_scan1<<<dim3(16, NCH), 256, 0, stream>>>(gi, gf, gtz, sums);
    k_scan2<<<16, 256, 0, stream>>>(sums, states);
    k_scan3<<<dim3(16, NCH), 256, 0, stream>>>(gi, gf, go, gtz, states, hbuf);
    k_rmsnorm<<<MTOT / 4, 256, 0, stream>>>(hbuf, scale, out);
}